// Round 6
// baseline (1327.283 us; speedup 1.0000x reference)
//
#include <hip/hip_runtime.h>
#include <hip/hip_bf16.h>

#define B_   4
#define T_   2048
#define D_   1024
#define HQ_  16
#define HKV_ 4
#define HD_  64
#define NQKV_ 1536

typedef __attribute__((ext_vector_type(4))) float f32x4;
typedef _Float16 f16x8 __attribute__((ext_vector_type(8)));
typedef __attribute__((ext_vector_type(8))) unsigned short u16x8;

static __device__ __forceinline__ float h2f(unsigned short u) {
    union { unsigned short u; _Float16 h; } c; c.u = u; return (float)c.h;
}
static __device__ __forceinline__ unsigned short f2h(float f) {
    union { _Float16 h; unsigned short u; } c; c.h = (_Float16)f; return c.u;
}

#define GLL16(gsrc, ldst) \
    __builtin_amdgcn_global_load_lds((const __attribute__((address_space(1))) unsigned int*)(gsrc), \
                                     (__attribute__((address_space(3))) unsigned int*)(ldst), 16, 0, 0)

// ---------------------------------------------------------------- cast f32->f16
__global__ __launch_bounds__(256) void k_cast(const float* __restrict__ in,
                                              unsigned short* __restrict__ out, int n4) {
    int i = blockIdx.x * blockDim.x + threadIdx.x;
    int stride = gridDim.x * blockDim.x;
    for (; i < n4; i += stride) {
        f32x4 v = ((const f32x4*)in)[i];
        unsigned long long r;
        r  = (unsigned long long)f2h(v.x);
        r |= (unsigned long long)f2h(v.y) << 16;
        r |= (unsigned long long)f2h(v.z) << 32;
        r |= (unsigned long long)f2h(v.w) << 48;
        ((unsigned long long*)out)[i] = r;
    }
}

// ---------------------------------------------------------------- GEMM  C = A(MxK) * B(NxK)^T  (verified)
template <bool F16OUT>
__global__ __launch_bounds__(256) void k_gemm_bt(const unsigned short* __restrict__ A,
                                                 const unsigned short* __restrict__ Bw,
                                                 void* __restrict__ Cv, int M, int N, int K) {
    __shared__ __attribute__((aligned(16))) unsigned short As[128 * 32];
    __shared__ __attribute__((aligned(16))) unsigned short Bs[128 * 32];
    const int tid = threadIdx.x;
    const int w = tid >> 6, lane = tid & 63;
    const int gq = lane >> 4, n16 = lane & 15;
    const long gm0 = (long)blockIdx.y * 128, gn0 = (long)blockIdx.x * 128;
    const int wm = (w >> 1) * 64, wn = (w & 1) * 64;

    f32x4 acc[4][4] = {};

    const int KT = K >> 5;
    const int srow0 = w * 32 + (lane >> 2);
    unsigned short* alds = &As[w * 1024];
    unsigned short* blds = &Bs[w * 1024];

    auto stage = [&](int kt) {
        const int k0 = kt * 32;
#pragma unroll
        for (int i = 0; i < 2; i++) {
            int row = srow0 + i * 16;
            int chk = (lane & 3) ^ ((row >> 1) & 3);
            GLL16(A  + (gm0 + row) * K + k0 + chk * 8, alds + i * 512);
            GLL16(Bw + (gn0 + row) * K + k0 + chk * 8, blds + i * 512);
        }
    };

    stage(0);
    for (int kt = 0; kt < KT; ++kt) {
        __syncthreads();
        f16x8 af[4], bf[4];
#pragma unroll
        for (int mf = 0; mf < 4; mf++) {
            int row = wm + mf * 16 + n16;
            int chk = gq ^ ((row >> 1) & 3);
            af[mf] = *(const f16x8*)&As[row * 32 + chk * 8];
        }
#pragma unroll
        for (int nf = 0; nf < 4; nf++) {
            int row = wn + nf * 16 + n16;
            int chk = gq ^ ((row >> 1) & 3);
            bf[nf] = *(const f16x8*)&Bs[row * 32 + chk * 8];
        }
#pragma unroll
        for (int mf = 0; mf < 4; mf++)
#pragma unroll
            for (int nf = 0; nf < 4; nf++)
                acc[mf][nf] = __builtin_amdgcn_mfma_f32_16x16x32_f16(af[mf], bf[nf], acc[mf][nf], 0, 0, 0);
        __syncthreads();
        if (kt + 1 < KT) stage(kt + 1);
    }

#pragma unroll
    for (int mf = 0; mf < 4; mf++)
#pragma unroll
        for (int nf = 0; nf < 4; nf++)
#pragma unroll
            for (int q = 0; q < 4; q++) {
                long r = gm0 + wm + mf * 16 + gq * 4 + q;
                long c = gn0 + wn + nf * 16 + n16;
                if (F16OUT)
                    ((unsigned short*)Cv)[r * N + c] = f2h(acc[mf][nf][q]);
                else
                    ((float*)Cv)[r * N + c] = acc[mf][nf][q];
            }
}

// ---------------------------------------------------------------- RoPE + scatter + V transpose (restored)
__global__ __launch_bounds__(256) void k_rope(const unsigned short* __restrict__ qkv,
                                              const float* __restrict__ cosb,
                                              const float* __restrict__ sinb,
                                              unsigned short* __restrict__ qs,
                                              unsigned short* __restrict__ kb,
                                              unsigned short* __restrict__ vt) {
    const int blk = blockIdx.x;
    const int b = blk >> 5;
    const int t0 = (blk & 31) * 64;
    const int tid = threadIdx.x;
    const float ALPHA = 0.125f * 1.44269504088896340736f; // HD^-0.5 * log2(e), folded into q

    for (int it = 0; it < 128; ++it) {
        int idx = it * 256 + tid;
        int p = idx & 511, tl = idx >> 9;
        int h = p >> 5, dp = p & 31;
        int t = t0 + tl;
        unsigned int v = *(const unsigned int*)&qkv[(long)(b * T_ + t) * NQKV_ + h * 64 + dp * 2];
        float q0 = h2f((unsigned short)v), q1 = h2f((unsigned short)(v >> 16));
        int d0 = dp * 2;
        float2 cc = *(const float2*)&cosb[t * 64 + d0];
        float2 ss = *(const float2*)&sinb[t * 64 + d0];
        float o0 = (q0 * cc.x - q1 * ss.x) * ALPHA;
        float o1 = (q1 * cc.y + q0 * ss.y) * ALPHA;
        unsigned int ov = (unsigned int)f2h(o0) | ((unsigned int)f2h(o1) << 16);
        *(unsigned int*)&qs[((long)(b * HQ_ + h) * T_ + t) * 64 + d0] = ov;
    }
    for (int it = 0; it < 32; ++it) {
        int idx = it * 256 + tid;
        int dp = idx & 31, g = (idx >> 5) & 3, tl = idx >> 7;
        int t = t0 + tl;
        unsigned int v = *(const unsigned int*)&qkv[(long)(b * T_ + t) * NQKV_ + 1024 + g * 128 + dp * 2];
        float k0 = h2f((unsigned short)v), k1 = h2f((unsigned short)(v >> 16));
        int d0 = dp * 2;
        float2 cc = *(const float2*)&cosb[t * 64 + d0];
        float2 ss = *(const float2*)&sinb[t * 64 + d0];
        float o0 = k0 * cc.x - k1 * ss.x;
        float o1 = k1 * cc.y + k0 * ss.y;
        unsigned int ov = (unsigned int)f2h(o0) | ((unsigned int)f2h(o1) << 16);
        *(unsigned int*)&kb[((long)(b * HKV_ + g) * T_ + t) * 64 + d0] = ov;
    }
    // V transpose: [t][d] -> [d][t]
    for (int it = 0; it < 8; ++it) {
        int idx = it * 256 + tid;
        int d = idx & 63, tc = (idx >> 6) & 7, g = idx >> 9;
        u16x8 vv;
#pragma unroll
        for (int j = 0; j < 8; ++j) {
            int t = t0 + tc * 8 + j;
            vv[j] = qkv[(long)(b * T_ + t) * NQKV_ + 1024 + g * 128 + 64 + d];
        }
        *(u16x8*)&vt[((long)(b * HKV_ + g) * 64 + d) * T_ + t0 + tc * 8] = vv;
    }
}

// ---------------------------------------------------------------- flash attention — BISECTION Test B
// Round-5 passing structure; SINGLE change: V read from vtb ([b][g][d][t]) via plain global loads.
__global__ __launch_bounds__(256) void k_attn(const unsigned short* __restrict__ qs,
                                              const unsigned short* __restrict__ kb,
                                              const unsigned short* __restrict__ vt,
                                              unsigned short* __restrict__ ao) {
    __shared__ __attribute__((aligned(16))) unsigned short Ks[64 * 64];
    __shared__ __attribute__((aligned(16))) unsigned short Ps[4][32 * 72];
    const int tid = threadIdx.x;
    const int w = tid >> 6, lane = tid & 63;
    const int gq = lane >> 4, n16 = lane & 15;
    const int bh = blockIdx.y;
    const int b = bh >> 4, h = bh & 15, g = h >> 2;
    const int qt0 = blockIdx.x * 128 + w * 32;

    f16x8 qf[2][2];
#pragma unroll
    for (int mf = 0; mf < 2; mf++)
#pragma unroll
        for (int ks = 0; ks < 2; ks++) {
            long t = qt0 + mf * 16 + n16;
            qf[mf][ks] = *(const f16x8*)&qs[((long)(b * HQ_ + h) * T_ + t) * 64 + ks * 32 + gq * 8];
        }

    f32x4 acc[2][4] = {};
    float rm[2][4], rl[2][4];
#pragma unroll
    for (int mf = 0; mf < 2; mf++)
#pragma unroll
        for (int q = 0; q < 4; q++) { rm[mf][q] = -1e30f; rl[mf][q] = 0.f; }

    const unsigned short* Kg = kb + (long)(b * HKV_ + g) * T_ * 64;
    const unsigned short* Vt = vt + (long)(b * HKV_ + g) * 64 * T_;   // + d*T_ + t

    unsigned short* klds = &Ks[w * 1024];
    const int strow0 = w * 16 + (lane >> 3);
    const int schk = lane & 7;

    auto stageK = [&](int kt) {
#pragma unroll
        for (int i = 0; i < 2; i++) {
            int row = strow0 + i * 8;
            int chk = schk ^ (row & 7);
            GLL16(Kg + (long)(kt * 64 + row) * 64 + chk * 8, klds + i * 512);
        }
    };

    stageK(0);
    for (int kt = 0; kt < 32; ++kt) {
        __syncthreads();
        // ---- S = Q K^T (verified)
        f16x8 kf[4][2];
#pragma unroll
        for (int j = 0; j < 4; j++)
#pragma unroll
            for (int ks = 0; ks < 2; ks++) {
                int row = j * 16 + n16;
                int c = (ks * 4 + gq) ^ (row & 7);
                kf[j][ks] = *(const f16x8*)&Ks[row * 64 + c * 8];
            }
        f32x4 s[2][4] = {};
#pragma unroll
        for (int mf = 0; mf < 2; mf++)
#pragma unroll
            for (int j = 0; j < 4; j++) {
                s[mf][j] = __builtin_amdgcn_mfma_f32_16x16x32_f16(qf[mf][0], kf[j][0], s[mf][j], 0, 0, 0);
                s[mf][j] = __builtin_amdgcn_mfma_f32_16x16x32_f16(qf[mf][1], kf[j][1], s[mf][j], 0, 0, 0);
            }
        // ---- online softmax (verified)
#pragma unroll
        for (int mf = 0; mf < 2; mf++)
#pragma unroll
            for (int q = 0; q < 4; q++) {
                float mx = fmaxf(fmaxf(s[mf][0][q], s[mf][1][q]), fmaxf(s[mf][2][q], s[mf][3][q]));
#pragma unroll
                for (int off = 1; off < 16; off <<= 1) mx = fmaxf(mx, __shfl_xor(mx, off, 64));
                float mnew = fmaxf(rm[mf][q], mx);
                float corr = __builtin_amdgcn_exp2f(rm[mf][q] - mnew);
                float rs = 0.f;
#pragma unroll
                for (int j = 0; j < 4; j++) {
                    float p = __builtin_amdgcn_exp2f(s[mf][j][q] - mnew);
                    s[mf][j][q] = p;
                    rs += p;
                }
#pragma unroll
                for (int off = 1; off < 16; off <<= 1) rs += __shfl_xor(rs, off, 64);
                rl[mf][q] = rl[mf][q] * corr + rs;
                rm[mf][q] = mnew;
#pragma unroll
                for (int dn = 0; dn < 4; dn++) acc[mf][dn][q] *= corr;
            }
        // ---- P write (verified)
        unsigned short* Pw = Ps[w];
#pragma unroll
        for (int mf = 0; mf < 2; mf++)
#pragma unroll
            for (int j = 0; j < 4; j++)
#pragma unroll
                for (int q = 0; q < 4; q++) {
                    int row = mf * 16 + gq * 4 + q;
                    Pw[row * 72 + j * 16 + n16] = f2h(s[mf][j][q]);
                }
        asm volatile("s_waitcnt lgkmcnt(0)" ::: "memory");
        __builtin_amdgcn_sched_barrier(0);
        // ---- Test B PV: P from LDS (verified), V from GLOBAL vtb (the suspect's content+region)
#pragma unroll 2
        for (int kc = 0; kc < 8; ++kc) {
            u16x8 vv[4];
#pragma unroll
            for (int dn = 0; dn < 4; dn++) {
                int d = dn * 16 + n16;
                vv[dn] = *(const u16x8*)&Vt[(long)d * T_ + kt * 64 + kc * 8];
            }
#pragma unroll
            for (int j = 0; j < 8; ++j) {
                int key = kc * 8 + j;
#pragma unroll
                for (int mf = 0; mf < 2; mf++)
#pragma unroll
                    for (int q = 0; q < 4; q++) {
                        float p = h2f(Pw[(mf * 16 + gq * 4 + q) * 72 + key]);
#pragma unroll
                        for (int dn = 0; dn < 4; dn++) acc[mf][dn][q] += p * h2f(vv[dn][j]);
                    }
            }
        }
        __syncthreads();
        if (kt + 1 < 32) stageK(kt + 1);
    }
    // ---- epilogue (verified)
#pragma unroll
    for (int mf = 0; mf < 2; mf++)
#pragma unroll
        for (int q = 0; q < 4; q++) {
            float inv = 1.0f / rl[mf][q];
            long t = qt0 + mf * 16 + gq * 4 + q;
#pragma unroll
            for (int dn = 0; dn < 4; dn++)
                ao[(long)(b * T_ + t) * D_ + h * 64 + dn * 16 + n16] = f2h(acc[mf][dn][q] * inv);
        }
}

// ---------------------------------------------------------------- launch
extern "C" void kernel_launch(void* const* d_in, const int* in_sizes, int n_in,
                              void* d_out, int out_size, void* d_ws, size_t ws_size,
                              hipStream_t stream) {
    const float* x    = (const float*)d_in[0];
    const float* cosb = (const float*)d_in[1];
    const float* sinb = (const float*)d_in[2];
    const float* Wq   = (const float*)d_in[3];
    const float* Wkv  = (const float*)d_in[4];
    const float* Wo   = (const float*)d_in[5];
    float* out = (float*)d_out;

    char* ws = (char*)d_ws;
    unsigned short* xb   = (unsigned short*)(ws);              // reused as attnout
    unsigned short* wcat = (unsigned short*)(ws + 16777216);   // [Wq ; Wkv]
    unsigned short* wob  = (unsigned short*)(ws + 19922944);
    unsigned short* qkvb = (unsigned short*)(ws + 22020096);
    unsigned short* qsb  = (unsigned short*)(ws + 47185920);
    // REGION SWAP (bisection): vtb now in the proven-good slot, kbuf in the suspect high slot.
    unsigned short* vtb  = (unsigned short*)(ws + 63963136);   // LOW  (proven backed, round 3/5)
    unsigned short* kbuf = (unsigned short*)(ws + 68157440);   // HIGH (suspect region — K corrupt => LARGE error)

    k_cast<<<2048, 256, 0, stream>>>(x,   xb,             (B_ * T_ * D_) / 4);
    k_cast<<<1024, 256, 0, stream>>>(Wq,  wcat,           (D_ * D_) / 4);
    k_cast<<<512,  256, 0, stream>>>(Wkv, wcat + D_ * D_, (512 * D_) / 4);
    k_cast<<<1024, 256, 0, stream>>>(Wo,  wob,            (D_ * D_) / 4);

    k_gemm_bt<true><<<dim3(NQKV_ / 128, (B_ * T_) / 128), 256, 0, stream>>>(xb, wcat, qkvb, B_ * T_, NQKV_, D_);
    k_rope<<<B_ * (T_ / 64), 256, 0, stream>>>(qkvb, cosb, sinb, qsb, kbuf, vtb);
    k_attn<<<dim3(T_ / 128, B_ * HQ_), 256, 0, stream>>>(qsb, kbuf, vtb, xb);
    k_gemm_bt<false><<<dim3(D_ / 128, (B_ * T_) / 128), 256, 0, stream>>>(xb, wob, out, B_ * T_, D_, D_);
}

// Round 7
// 348.086 us; speedup vs baseline: 3.8131x; 3.8131x over previous
//
#include <hip/hip_runtime.h>
#include <hip/hip_bf16.h>

#define B_   4
#define T_   2048
#define D_   1024
#define HQ_  16
#define HKV_ 4
#define HD_  64
#define NQKV_ 1536

typedef __attribute__((ext_vector_type(4))) float f32x4;
typedef _Float16 f16x8 __attribute__((ext_vector_type(8)));
typedef __attribute__((ext_vector_type(8))) unsigned short u16x8;

static __device__ __forceinline__ float h2f(unsigned short u) {
    union { unsigned short u; _Float16 h; } c; c.u = u; return (float)c.h;
}
static __device__ __forceinline__ unsigned short f2h(float f) {
    union { _Float16 h; unsigned short u; } c; c.h = (_Float16)f; return c.u;
}

#define GLL16(gsrc, ldst) \
    __builtin_amdgcn_global_load_lds((const __attribute__((address_space(1))) unsigned int*)(gsrc), \
                                     (__attribute__((address_space(3))) unsigned int*)(ldst), 16, 0, 0)

// ---------------------------------------------------------------- cast f32->f16
__global__ __launch_bounds__(256) void k_cast(const float* __restrict__ in,
                                              unsigned short* __restrict__ out, int n4) {
    int i = blockIdx.x * blockDim.x + threadIdx.x;
    int stride = gridDim.x * blockDim.x;
    for (; i < n4; i += stride) {
        f32x4 v = ((const f32x4*)in)[i];
        unsigned long long r;
        r  = (unsigned long long)f2h(v.x);
        r |= (unsigned long long)f2h(v.y) << 16;
        r |= (unsigned long long)f2h(v.z) << 32;
        r |= (unsigned long long)f2h(v.w) << 48;
        ((unsigned long long*)out)[i] = r;
    }
}

// ---------------------------------------------------------------- GEMM  C = A(MxK) * B(NxK)^T  (verified)
template <bool F16OUT>
__global__ __launch_bounds__(256) void k_gemm_bt(const unsigned short* __restrict__ A,
                                                 const unsigned short* __restrict__ Bw,
                                                 void* __restrict__ Cv, int M, int N, int K) {
    __shared__ __attribute__((aligned(16))) unsigned short As[128 * 32];
    __shared__ __attribute__((aligned(16))) unsigned short Bs[128 * 32];
    const int tid = threadIdx.x;
    const int w = tid >> 6, lane = tid & 63;
    const int gq = lane >> 4, n16 = lane & 15;
    const long gm0 = (long)blockIdx.y * 128, gn0 = (long)blockIdx.x * 128;
    const int wm = (w >> 1) * 64, wn = (w & 1) * 64;

    f32x4 acc[4][4] = {};

    const int KT = K >> 5;
    const int srow0 = w * 32 + (lane >> 2);
    unsigned short* alds = &As[w * 1024];
    unsigned short* blds = &Bs[w * 1024];

    auto stage = [&](int kt) {
        const int k0 = kt * 32;
#pragma unroll
        for (int i = 0; i < 2; i++) {
            int row = srow0 + i * 16;
            int chk = (lane & 3) ^ ((row >> 1) & 3);
            GLL16(A  + (gm0 + row) * K + k0 + chk * 8, alds + i * 512);
            GLL16(Bw + (gn0 + row) * K + k0 + chk * 8, blds + i * 512);
        }
    };

    stage(0);
    for (int kt = 0; kt < KT; ++kt) {
        __syncthreads();
        f16x8 af[4], bf[4];
#pragma unroll
        for (int mf = 0; mf < 4; mf++) {
            int row = wm + mf * 16 + n16;
            int chk = gq ^ ((row >> 1) & 3);
            af[mf] = *(const f16x8*)&As[row * 32 + chk * 8];
        }
#pragma unroll
        for (int nf = 0; nf < 4; nf++) {
            int row = wn + nf * 16 + n16;
            int chk = gq ^ ((row >> 1) & 3);
            bf[nf] = *(const f16x8*)&Bs[row * 32 + chk * 8];
        }
#pragma unroll
        for (int mf = 0; mf < 4; mf++)
#pragma unroll
            for (int nf = 0; nf < 4; nf++)
                acc[mf][nf] = __builtin_amdgcn_mfma_f32_16x16x32_f16(af[mf], bf[nf], acc[mf][nf], 0, 0, 0);
        __syncthreads();
        if (kt + 1 < KT) stage(kt + 1);
    }

#pragma unroll
    for (int mf = 0; mf < 4; mf++)
#pragma unroll
        for (int nf = 0; nf < 4; nf++)
#pragma unroll
            for (int q = 0; q < 4; q++) {
                long r = gm0 + wm + mf * 16 + gq * 4 + q;
                long c = gn0 + wn + nf * 16 + n16;
                if (F16OUT)
                    ((unsigned short*)Cv)[r * N + c] = f2h(acc[mf][nf][q]);
                else
                    ((float*)Cv)[r * N + c] = acc[mf][nf][q];
            }
}

// ---------------------------------------------------------------- RoPE + scatter + V transpose (verified)
__global__ __launch_bounds__(256) void k_rope(const unsigned short* __restrict__ qkv,
                                              const float* __restrict__ cosb,
                                              const float* __restrict__ sinb,
                                              unsigned short* __restrict__ qs,
                                              unsigned short* __restrict__ kb,
                                              unsigned short* __restrict__ vt) {
    const int blk = blockIdx.x;
    const int b = blk >> 5;
    const int t0 = (blk & 31) * 64;
    const int tid = threadIdx.x;
    const float ALPHA = 0.125f * 1.44269504088896340736f; // HD^-0.5 * log2(e), folded into q

    for (int it = 0; it < 128; ++it) {
        int idx = it * 256 + tid;
        int p = idx & 511, tl = idx >> 9;
        int h = p >> 5, dp = p & 31;
        int t = t0 + tl;
        unsigned int v = *(const unsigned int*)&qkv[(long)(b * T_ + t) * NQKV_ + h * 64 + dp * 2];
        float q0 = h2f((unsigned short)v), q1 = h2f((unsigned short)(v >> 16));
        int d0 = dp * 2;
        float2 cc = *(const float2*)&cosb[t * 64 + d0];
        float2 ss = *(const float2*)&sinb[t * 64 + d0];
        float o0 = (q0 * cc.x - q1 * ss.x) * ALPHA;
        float o1 = (q1 * cc.y + q0 * ss.y) * ALPHA;
        unsigned int ov = (unsigned int)f2h(o0) | ((unsigned int)f2h(o1) << 16);
        *(unsigned int*)&qs[((long)(b * HQ_ + h) * T_ + t) * 64 + d0] = ov;
    }
    for (int it = 0; it < 32; ++it) {
        int idx = it * 256 + tid;
        int dp = idx & 31, g = (idx >> 5) & 3, tl = idx >> 7;
        int t = t0 + tl;
        unsigned int v = *(const unsigned int*)&qkv[(long)(b * T_ + t) * NQKV_ + 1024 + g * 128 + dp * 2];
        float k0 = h2f((unsigned short)v), k1 = h2f((unsigned short)(v >> 16));
        int d0 = dp * 2;
        float2 cc = *(const float2*)&cosb[t * 64 + d0];
        float2 ss = *(const float2*)&sinb[t * 64 + d0];
        float o0 = k0 * cc.x - k1 * ss.x;
        float o1 = k1 * cc.y + k0 * ss.y;
        unsigned int ov = (unsigned int)f2h(o0) | ((unsigned int)f2h(o1) << 16);
        *(unsigned int*)&kb[((long)(b * HKV_ + g) * T_ + t) * 64 + d0] = ov;
    }
    // V transpose: [t][d] -> [d][t]
    for (int it = 0; it < 8; ++it) {
        int idx = it * 256 + tid;
        int d = idx & 63, tc = (idx >> 6) & 7, g = idx >> 9;
        u16x8 vv;
#pragma unroll
        for (int j = 0; j < 8; ++j) {
            int t = t0 + tc * 8 + j;
            vv[j] = qkv[(long)(b * T_ + t) * NQKV_ + 1024 + g * 128 + 64 + d];
        }
        *(u16x8*)&vt[((long)(b * HKV_ + g) * 64 + d) * T_ + t0 + tc * 8] = vv;
    }
}

// ---------------------------------------------------------------- flash attention (MFMA PV restored)
// K via GLL16 (verified); V fragments DIRECT from global vtb (verified addresses, no GLL16-V);
// P via LDS round-trip (write+content verified; pf uses the QK^T-verified A-fragment algebra).
__global__ __launch_bounds__(256) void k_attn(const unsigned short* __restrict__ qs,
                                              const unsigned short* __restrict__ kb,
                                              const unsigned short* __restrict__ vt,
                                              unsigned short* __restrict__ ao) {
    __shared__ __attribute__((aligned(16))) unsigned short Ks[64 * 64];
    __shared__ __attribute__((aligned(16))) unsigned short Ps[4][32 * 72];
    const int tid = threadIdx.x;
    const int w = tid >> 6, lane = tid & 63;
    const int gq = lane >> 4, n16 = lane & 15;
    const int bh = blockIdx.y;
    const int b = bh >> 4, h = bh & 15, g = h >> 2;
    const int qt0 = blockIdx.x * 128 + w * 32;

    f16x8 qf[2][2];
#pragma unroll
    for (int mf = 0; mf < 2; mf++)
#pragma unroll
        for (int ks = 0; ks < 2; ks++) {
            long t = qt0 + mf * 16 + n16;
            qf[mf][ks] = *(const f16x8*)&qs[((long)(b * HQ_ + h) * T_ + t) * 64 + ks * 32 + gq * 8];
        }

    f32x4 acc[2][4] = {};
    float rm[2][4], rl[2][4];
#pragma unroll
    for (int mf = 0; mf < 2; mf++)
#pragma unroll
        for (int q = 0; q < 4; q++) { rm[mf][q] = -1e30f; rl[mf][q] = 0.f; }

    const unsigned short* Kg = kb + (long)(b * HKV_ + g) * T_ * 64;
    const unsigned short* Vt = vt + (long)(b * HKV_ + g) * 64 * T_;   // + d*T_ + t

    unsigned short* klds = &Ks[w * 1024];
    const int strow0 = w * 16 + (lane >> 3);
    const int schk = lane & 7;

    auto stageK = [&](int kt) {
#pragma unroll
        for (int i = 0; i < 2; i++) {
            int row = strow0 + i * 8;
            int chk = schk ^ (row & 7);
            GLL16(Kg + (long)(kt * 64 + row) * 64 + chk * 8, klds + i * 512);
        }
    };

    stageK(0);
    for (int kt = 0; kt < 32; ++kt) {
        __syncthreads();
        // ---- S = Q K^T (verified)
        f16x8 kf[4][2];
#pragma unroll
        for (int j = 0; j < 4; j++)
#pragma unroll
            for (int ks = 0; ks < 2; ks++) {
                int row = j * 16 + n16;
                int c = (ks * 4 + gq) ^ (row & 7);
                kf[j][ks] = *(const f16x8*)&Ks[row * 64 + c * 8];
            }
        f32x4 s[2][4] = {};
#pragma unroll
        for (int mf = 0; mf < 2; mf++)
#pragma unroll
            for (int j = 0; j < 4; j++) {
                s[mf][j] = __builtin_amdgcn_mfma_f32_16x16x32_f16(qf[mf][0], kf[j][0], s[mf][j], 0, 0, 0);
                s[mf][j] = __builtin_amdgcn_mfma_f32_16x16x32_f16(qf[mf][1], kf[j][1], s[mf][j], 0, 0, 0);
            }
        // ---- V fragments direct from global (issued early; latency hides under softmax)
        f16x8 vf[4][2];
#pragma unroll
        for (int dn = 0; dn < 4; dn++)
#pragma unroll
            for (int ks = 0; ks < 2; ks++)
                vf[dn][ks] = *(const f16x8*)&Vt[(long)(dn * 16 + n16) * T_ + kt * 64 + (ks * 4 + gq) * 8];
        // ---- online softmax (verified)
#pragma unroll
        for (int mf = 0; mf < 2; mf++)
#pragma unroll
            for (int q = 0; q < 4; q++) {
                float mx = fmaxf(fmaxf(s[mf][0][q], s[mf][1][q]), fmaxf(s[mf][2][q], s[mf][3][q]));
#pragma unroll
                for (int off = 1; off < 16; off <<= 1) mx = fmaxf(mx, __shfl_xor(mx, off, 64));
                float mnew = fmaxf(rm[mf][q], mx);
                float corr = __builtin_amdgcn_exp2f(rm[mf][q] - mnew);
                float rs = 0.f;
#pragma unroll
                for (int j = 0; j < 4; j++) {
                    float p = __builtin_amdgcn_exp2f(s[mf][j][q] - mnew);
                    s[mf][j][q] = p;
                    rs += p;
                }
#pragma unroll
                for (int off = 1; off < 16; off <<= 1) rs += __shfl_xor(rs, off, 64);
                rl[mf][q] = rl[mf][q] * corr + rs;
                rm[mf][q] = mnew;
#pragma unroll
                for (int dn = 0; dn < 4; dn++) acc[mf][dn][q] *= corr;
            }
        // ---- P write (verified)
        unsigned short* Pw = Ps[w];
#pragma unroll
        for (int mf = 0; mf < 2; mf++)
#pragma unroll
            for (int j = 0; j < 4; j++)
#pragma unroll
                for (int q = 0; q < 4; q++) {
                    int row = mf * 16 + gq * 4 + q;
                    Pw[row * 72 + j * 16 + n16] = f2h(s[mf][j][q]);
                }
        asm volatile("s_waitcnt lgkmcnt(0)" ::: "memory");
        __builtin_amdgcn_sched_barrier(0);
        // ---- PV via MFMA: pf (A-frag, QK^T-verified algebra) x vf (B-frag, kf-verified layout)
        f16x8 pf[2][2];
#pragma unroll
        for (int mf = 0; mf < 2; mf++)
#pragma unroll
            for (int ks = 0; ks < 2; ks++)
                pf[mf][ks] = *(const f16x8*)&Pw[(mf * 16 + n16) * 72 + ks * 32 + gq * 8];
#pragma unroll
        for (int mf = 0; mf < 2; mf++)
#pragma unroll
            for (int dn = 0; dn < 4; dn++) {
                acc[mf][dn] = __builtin_amdgcn_mfma_f32_16x16x32_f16(pf[mf][0], vf[dn][0], acc[mf][dn], 0, 0, 0);
                acc[mf][dn] = __builtin_amdgcn_mfma_f32_16x16x32_f16(pf[mf][1], vf[dn][1], acc[mf][dn], 0, 0, 0);
            }
        __syncthreads();
        if (kt + 1 < 32) stageK(kt + 1);
    }
    // ---- epilogue (verified)
#pragma unroll
    for (int mf = 0; mf < 2; mf++)
#pragma unroll
        for (int q = 0; q < 4; q++) {
            float inv = 1.0f / rl[mf][q];
            long t = qt0 + mf * 16 + gq * 4 + q;
#pragma unroll
            for (int dn = 0; dn < 4; dn++)
                ao[(long)(b * T_ + t) * D_ + h * 64 + dn * 16 + n16] = f2h(acc[mf][dn][q] * inv);
        }
}

// ---------------------------------------------------------------- launch
extern "C" void kernel_launch(void* const* d_in, const int* in_sizes, int n_in,
                              void* d_out, int out_size, void* d_ws, size_t ws_size,
                              hipStream_t stream) {
    const float* x    = (const float*)d_in[0];
    const float* cosb = (const float*)d_in[1];
    const float* sinb = (const float*)d_in[2];
    const float* Wq   = (const float*)d_in[3];
    const float* Wkv  = (const float*)d_in[4];
    const float* Wo   = (const float*)d_in[5];
    float* out = (float*)d_out;

    char* ws = (char*)d_ws;
    unsigned short* xb   = (unsigned short*)(ws);              // reused as attnout
    unsigned short* wcat = (unsigned short*)(ws + 16777216);   // [Wq ; Wkv]
    unsigned short* wob  = (unsigned short*)(ws + 19922944);
    unsigned short* qkvb = (unsigned short*)(ws + 22020096);
    unsigned short* qsb  = (unsigned short*)(ws + 47185920);
    unsigned short* vtb  = (unsigned short*)(ws + 63963136);   // (verified layout, round 6)
    unsigned short* kbuf = (unsigned short*)(ws + 68157440);   // (region verified, round 6)

    k_cast<<<2048, 256, 0, stream>>>(x,   xb,             (B_ * T_ * D_) / 4);
    k_cast<<<1024, 256, 0, stream>>>(Wq,  wcat,           (D_ * D_) / 4);
    k_cast<<<512,  256, 0, stream>>>(Wkv, wcat + D_ * D_, (512 * D_) / 4);
    k_cast<<<1024, 256, 0, stream>>>(Wo,  wob,            (D_ * D_) / 4);

    k_gemm_bt<true><<<dim3(NQKV_ / 128, (B_ * T_) / 128), 256, 0, stream>>>(xb, wcat, qkvb, B_ * T_, NQKV_, D_);
    k_rope<<<B_ * (T_ / 64), 256, 0, stream>>>(qkvb, cosb, sinb, qsb, kbuf, vtb);
    k_attn<<<dim3(T_ / 128, B_ * HQ_), 256, 0, stream>>>(qsb, kbuf, vtb, xb);
    k_gemm_bt<false><<<dim3(D_ / 128, (B_ * T_) / 128), 256, 0, stream>>>(xb, wob, out, B_ * T_, D_, D_);
}